// Round 1
// 1766.768 us; speedup vs baseline: 1.1767x; 1.1767x over previous
//
#include <hip/hip_runtime.h>
#include <math.h>

#define NB 2048
#define NT 64
#define DD 1024
#define HH 512
#define KTOP 15
#define KC 16
#define NCHUNK (DD / KC)

typedef __attribute__((ext_vector_type(8))) short bf16x8;
typedef __attribute__((ext_vector_type(4))) float f32x4;

__device__ __forceinline__ unsigned short f2bf(float f) {
  unsigned u = __float_as_uint(f);
  unsigned r = u + 0x7fffu + ((u >> 16) & 1u);
  return (unsigned short)(r >> 16);
}
__device__ __forceinline__ float bf2f(unsigned short h) {
  return __uint_as_float(((unsigned)h) << 16);
}
__device__ __forceinline__ float4 sum4seg(const float* __restrict__ p, int n) {
  float4 a = *(const float4*)(p + n);
  float4 b = *(const float4*)(p + 512 + n);
  float4 c = *(const float4*)(p + 1024 + n);
  float4 d = *(const float4*)(p + 1536 + n);
  float4 r;
  r.x = a.x + b.x + c.x + d.x;
  r.y = a.y + b.y + c.y + d.y;
  r.z = a.z + b.z + c.z + d.z;
  r.w = a.w + b.w + c.w + d.w;
  return r;
}

// ---------------------------------------------------------------------------
// Prep: c1 partials [4][512], c2 partials [4][512] (b1 folded into seg 0),
// plus transposed bf16 hi/lo split of (gamma (.) w1): Wt[n][k], n=0..511.
// grid dim3(2,4): blockIdx.x -> 256 hidden cols, blockIdx.y -> 256-K segment.
// Deterministic (no atomics).
// ---------------------------------------------------------------------------
__global__ void prep_kernel(const float* __restrict__ w1,
                            const float* __restrict__ gamma,
                            const float* __restrict__ beta,
                            const float* __restrict__ b1,
                            float* __restrict__ c1p,
                            float* __restrict__ c2p,
                            unsigned short* __restrict__ wth,
                            unsigned short* __restrict__ wtl) {
  const int j = blockIdx.x * 256 + threadIdx.x;  // hidden col 0..511
  const int d0 = blockIdx.y * 256;               // K segment base
  float a = 0.f, cb = 0.f;
  for (int dd = 0; dd < 256; dd += 8) {
    unsigned hw[4], lw[4];
#pragma unroll
    for (int i = 0; i < 8; ++i) {
      const int d = d0 + dd + i;
      const float wv = w1[d * HH + j];
      a = fmaf(gamma[d], wv, a);
      cb = fmaf(beta[d], wv, cb);
      const float gw = gamma[d] * wv;
      const unsigned short hv = f2bf(gw);
      const unsigned short lv = f2bf(gw - bf2f(hv));
      if ((i & 1) == 0) {
        hw[i >> 1] = (unsigned)hv;
        lw[i >> 1] = (unsigned)lv;
      } else {
        hw[i >> 1] |= ((unsigned)hv << 16);
        lw[i >> 1] |= ((unsigned)lv << 16);
      }
    }
    if (wth) {
      uint4 H = {hw[0], hw[1], hw[2], hw[3]};
      uint4 L = {lw[0], lw[1], lw[2], lw[3]};
      *(uint4*)(wth + (size_t)j * DD + d0 + dd) = H;
      *(uint4*)(wtl + (size_t)j * DD + d0 + dd) = L;
    }
  }
  c1p[blockIdx.y * HH + j] = a;
  c2p[blockIdx.y * HH + j] = cb + ((blockIdx.y == 0) ? b1[j] : 0.f);
}

// ---------------------------------------------------------------------------
// Fused MFMA kernel: per block = one batch (64 tokens).
// GEMM 64x512x1024 via bf16 MFMA with 3-term error-compensated split
// (Ah*Bh + Ah*Bl + Al*Bh, fp32 accumulate). LayerNorm folded into epilogue.
// Stats (s1/s2/colsum) computed from the fp32 registers at stage time (exact).
// Sorted top-16 min-gap test: gap < 1e-4 -> flag for fp32 fallback kernel.
// 8 waves: wave w owns hidden cols [w*64, w*64+64), all 64 tokens (acc 4x4).
// LDS A tile: [64][136] ushort (pad -> b128 read/write at bank floor).
// ---------------------------------------------------------------------------
__global__ __launch_bounds__(512, 2) void fused_kernel(
    const float* __restrict__ tokens,
    const float* __restrict__ c1p,
    const float* __restrict__ c2p,
    const float* __restrict__ w2,
    const unsigned short* __restrict__ wth,
    const unsigned short* __restrict__ wtl,
    int* __restrict__ flags,
    float* __restrict__ out) {
  __shared__ __align__(16) unsigned short Ahi[NT][136];  // 17408 B
  __shared__ __align__(16) unsigned short Alo[NT][136];  // 17408 B
  __shared__ float colsum[DD];                           // 4 KiB
  __shared__ float slab[8][128];                         // 4 KiB (reused as selh)
  __shared__ float r_s[NT], rmu_s[NT];
  __shared__ float scp[8][NT];                           // 2 KiB
  __shared__ int topk_s[KTOP];

  const int tid = threadIdx.x;
  const int b = blockIdx.x;
  const int w = tid >> 6;    // wave 0..7 -> hidden cols w*64..
  const int l = tid & 63;
  const int lr = l & 15;     // MFMA row/col-in-tile lane index
  const int lg = l >> 4;     // MFMA k-group 0..3
  const int st = tid >> 3;   // staging token 0..63
  const int k16 = tid & 7;   // staging k-slot (16 floats)

  colsum[tid] = 0.f;
  colsum[tid + 512] = 0.f;

  f32x4 acc[4][4];
#pragma unroll
  for (int mt = 0; mt < 4; ++mt)
#pragma unroll
    for (int nt = 0; nt < 4; ++nt)
      acc[mt][nt] = (f32x4){0.f, 0.f, 0.f, 0.f};

  const float* tokp = tokens + (size_t)b * (NT * DD) + st * DD + (k16 << 4);
  float4 p0 = *(const float4*)(tokp);
  float4 p1 = *(const float4*)(tokp + 4);
  float4 p2 = *(const float4*)(tokp + 8);
  float4 p3 = *(const float4*)(tokp + 12);

  float s1r = 0.f, s2r = 0.f;

  for (int c = 0; c < 8; ++c) {
    float vsa[16] = {p0.x, p0.y, p0.z, p0.w, p1.x, p1.y, p1.z, p1.w,
                     p2.x, p2.y, p2.z, p2.w, p3.x, p3.y, p3.z, p3.w};
    // per-token stats (exact fp32)
#pragma unroll
    for (int i = 0; i < 16; ++i) {
      s1r += vsa[i];
      s2r = fmaf(vsa[i], vsa[i], s2r);
    }
    // colsum: reduce across this wave's 8 tokens (lanes differ in l>>3)
    float cs[16];
#pragma unroll
    for (int i = 0; i < 16; ++i) cs[i] = vsa[i];
#pragma unroll
    for (int off = 8; off <= 32; off <<= 1)
#pragma unroll
      for (int i = 0; i < 16; ++i) cs[i] += __shfl_xor(cs[i], off);
    if (l < 8) {  // lane l holds k-slot l's sums; static indices only
      float4 t0 = {cs[0], cs[1], cs[2], cs[3]};
      float4 t1 = {cs[4], cs[5], cs[6], cs[7]};
      float4 t2 = {cs[8], cs[9], cs[10], cs[11]};
      float4 t3 = {cs[12], cs[13], cs[14], cs[15]};
      *(float4*)&slab[w][(l << 4) + 0] = t0;
      *(float4*)&slab[w][(l << 4) + 4] = t1;
      *(float4*)&slab[w][(l << 4) + 8] = t2;
      *(float4*)&slab[w][(l << 4) + 12] = t3;
    }
    // bf16 hi/lo split -> LDS
    {
      unsigned hw[8], lw[8];
#pragma unroll
      for (int i = 0; i < 8; ++i) {
        const unsigned short h0 = f2bf(vsa[2 * i]);
        const unsigned short h1 = f2bf(vsa[2 * i + 1]);
        const unsigned short e0 = f2bf(vsa[2 * i] - bf2f(h0));
        const unsigned short e1 = f2bf(vsa[2 * i + 1] - bf2f(h1));
        hw[i] = (unsigned)h0 | ((unsigned)h1 << 16);
        lw[i] = (unsigned)e0 | ((unsigned)e1 << 16);
      }
      uint4 H0 = {hw[0], hw[1], hw[2], hw[3]};
      uint4 H1 = {hw[4], hw[5], hw[6], hw[7]};
      uint4 L0 = {lw[0], lw[1], lw[2], lw[3]};
      uint4 L1 = {lw[4], lw[5], lw[6], lw[7]};
      *(uint4*)&Ahi[st][(k16 << 4) + 0] = H0;
      *(uint4*)&Ahi[st][(k16 << 4) + 8] = H1;
      *(uint4*)&Alo[st][(k16 << 4) + 0] = L0;
      *(uint4*)&Alo[st][(k16 << 4) + 8] = L1;
    }
    __syncthreads();  // A tile + slab visible

    // prefetch next chunk (latency hidden under MFMA phase)
    if (c + 1 < 8) {
      const float* np = tokp + (c + 1) * 128;
      p0 = *(const float4*)(np);
      p1 = *(const float4*)(np + 4);
      p2 = *(const float4*)(np + 8);
      p3 = *(const float4*)(np + 12);
    }
    // combine per-wave colsum partials
    if (tid < 128) {
      colsum[(c << 7) + tid] += slab[0][tid] + slab[1][tid] + slab[2][tid] +
                                slab[3][tid] + slab[4][tid] + slab[5][tid] +
                                slab[6][tid] + slab[7][tid];
    }

    const int kb = c << 7;
#pragma unroll
    for (int ks = 0; ks < 4; ++ks) {
      bf16x8 ah[4], al[4];
#pragma unroll
      for (int mt = 0; mt < 4; ++mt) {
        ah[mt] = *(const bf16x8*)&Ahi[(mt << 4) + lr][(ks << 5) + (lg << 3)];
        al[mt] = *(const bf16x8*)&Alo[(mt << 4) + lr][(ks << 5) + (lg << 3)];
      }
#pragma unroll
      for (int nt = 0; nt < 4; ++nt) {
        const int boff = (((w << 6) + (nt << 4) + lr) << 10) + kb + (ks << 5) + (lg << 3);
        bf16x8 bh = *(const bf16x8*)(wth + boff);
        bf16x8 bl = *(const bf16x8*)(wtl + boff);
#pragma unroll
        for (int mt = 0; mt < 4; ++mt) {
          acc[mt][nt] = __builtin_amdgcn_mfma_f32_16x16x32_bf16(ah[mt], bh, acc[mt][nt], 0, 0, 0);
          acc[mt][nt] = __builtin_amdgcn_mfma_f32_16x16x32_bf16(ah[mt], bl, acc[mt][nt], 0, 0, 0);
          acc[mt][nt] = __builtin_amdgcn_mfma_f32_16x16x32_bf16(al[mt], bh, acc[mt][nt], 0, 0, 0);
        }
      }
    }
    __syncthreads();  // A reads done before next stage overwrites
  }

  // finalize per-token mean / rsqrt (threads of token st are consecutive lanes)
  s1r += __shfl_xor(s1r, 1); s1r += __shfl_xor(s1r, 2); s1r += __shfl_xor(s1r, 4);
  s2r += __shfl_xor(s2r, 1); s2r += __shfl_xor(s2r, 2); s2r += __shfl_xor(s2r, 4);
  if (k16 == 0) {
    const float mu = s1r * (1.0f / DD);
    const float var = s2r * (1.0f / DD) - mu * mu;
    const float r = 1.0f / sqrtf(var + 1e-5f);
    r_s[st] = r;
    rmu_s[st] = r * mu;
  }
  __syncthreads();

  // epilogue: h = relu(r*acc - r*mu*c1 + c2b); score partials -> scp[w][token]
  {
    float c1v[4], c2v[4], w2v[4];
#pragma unroll
    for (int nt = 0; nt < 4; ++nt) {
      const int n = (w << 6) + (nt << 4) + lr;
      c1v[nt] = c1p[n] + c1p[512 + n] + c1p[1024 + n] + c1p[1536 + n];
      c2v[nt] = c2p[n] + c2p[512 + n] + c2p[1024 + n] + c2p[1536 + n];
      w2v[nt] = w2[n];
    }
    float sp[4][4];
#pragma unroll
    for (int mt = 0; mt < 4; ++mt)
#pragma unroll
      for (int rg = 0; rg < 4; ++rg) {
        const int tk = (mt << 4) + (lg << 2) + rg;  // C/D row = token-in-tile
        const float r = r_s[tk], rm = rmu_s[tk];
        float s = 0.f;
#pragma unroll
        for (int nt = 0; nt < 4; ++nt) {
          float h = fmaf(r, acc[mt][nt][rg], fmaf(-rm, c1v[nt], c2v[nt]));
          h = fmaxf(h, 0.f);
          s = fmaf(h, w2v[nt], s);
        }
        sp[mt][rg] = s;
      }
#pragma unroll
    for (int off = 1; off <= 8; off <<= 1)
#pragma unroll
      for (int mt = 0; mt < 4; ++mt)
#pragma unroll
        for (int rg = 0; rg < 4; ++rg)
          sp[mt][rg] += __shfl_xor(sp[mt][rg], off);
    if (lr == 0) {
#pragma unroll
      for (int mt = 0; mt < 4; ++mt)
#pragma unroll
        for (int rg = 0; rg < 4; ++rg)
          scp[w][(mt << 4) + (lg << 2) + rg] = sp[mt][rg];
    }
  }
  __syncthreads();

  // wave-0 top-16 (sorted): record top-15, flag if any adjacent gap < 1e-4
  if (tid < 64) {
    float s = scp[0][tid] + scp[1][tid] + scp[2][tid] + scp[3][tid] +
              scp[4][tid] + scp[5][tid] + scp[6][tid] + scp[7][tid];
    int idx = tid;
    float prev = 0.f, mingap = 1e30f;
    for (int it = 0; it < 16; ++it) {
      float bs = s;
      int bi = idx;
#pragma unroll
      for (int off = 32; off > 0; off >>= 1) {
        const float os = __shfl_xor(bs, off);
        const int oi = __shfl_xor(bi, off);
        if (os > bs || (os == bs && oi < bi)) { bs = os; bi = oi; }
      }
      if (it < KTOP && tid == 0) topk_s[it] = bi;
      if (it > 0) mingap = fminf(mingap, prev - bs);
      prev = bs;
      if (idx == bi) s = -INFINITY;
    }
    if (tid == 0) flags[b] = (mingap < 1e-4f) ? 1 : 0;
  }
  __syncthreads();

  // output: row 0 = background mean, rows 1..15 = gathered top-k tokens
  {
    const int half = tid >> 8;  // 0: even rows, 1: odd rows
    const int q = tid & 255;
    const float* tb = tokens + (size_t)b * (NT * DD);
    float* ob = out + (size_t)b * (16 * DD);
    float sx = 0.f, sy = 0.f, sz = 0.f, sw = 0.f;
#pragma unroll
    for (int i = 0; i < 8; ++i) {
      const int rI = (i << 1) + half;
      if (rI >= 1) {
        const int tt = topk_s[rI - 1];
        float4 v = *(const float4*)(tb + (size_t)tt * DD + (q << 2));
        *(float4*)(ob + (size_t)rI * DD + (q << 2)) = v;
        sx += v.x; sy += v.y; sz += v.z; sw += v.w;
      }
    }
    float* selh = &slab[0][0];  // reuse slab (1024 floats)
    if (half == 1) {
      float4 sv = {sx, sy, sz, sw};
      *(float4*)(selh + (q << 2)) = sv;
    }
    __syncthreads();
    if (half == 0) {
      const float4 o = *(const float4*)(selh + (q << 2));
      const float4 csv = *(const float4*)(&colsum[q << 2]);
      const float inv = 1.0f / 49.0f;  // bg_count = 64 - 15
      float4 bg;
      bg.x = (csv.x - sx - o.x) * inv;
      bg.y = (csv.y - sy - o.y) * inv;
      bg.z = (csv.z - sz - o.z) * inv;
      bg.w = (csv.w - sw - o.w) * inv;
      *(float4*)(ob + (q << 2)) = bg;
    }
  }
}

// ---------------------------------------------------------------------------
// fp32 fallback (the previous harness-verified kernel, verbatim except:
// flags early-exit, c1/c2 read as 4-segment partial sums).
// Runs only for batches whose score min-gap was below threshold.
// ---------------------------------------------------------------------------
__global__ __launch_bounds__(256, 2) void score_gather_kernel(
    const float* __restrict__ tokens,
    const float* __restrict__ w1,
    const float* __restrict__ w2,
    const float* __restrict__ gamma,
    const float* __restrict__ c1p,
    const float* __restrict__ c2p,
    const int* __restrict__ flags,
    float* __restrict__ out) {
  if (flags != nullptr && flags[blockIdx.x] == 0) return;

  __shared__ float Asm[KC][NT];
  __shared__ float Bsm[KC][HH];
  __shared__ float colsum[DD];
  __shared__ float gam[DD];
  __shared__ float s1p[4][NT];
  __shared__ float s2p[4][NT];
  __shared__ float r_s[NT];
  __shared__ float rmu_s[NT];
  __shared__ float scp[32][NT];
  __shared__ int topk_s[KTOP];

  const int tid = threadIdx.x;
  const int b = blockIdx.x;
  const int tg = tid & 7;
  const int hg = tid >> 3;

  {
    float4 g = *(const float4*)(gamma + tid * 4);
    *(float4*)(&gam[tid * 4]) = g;
    float4 z = {0.f, 0.f, 0.f, 0.f};
    *(float4*)(&colsum[tid * 4]) = z;
  }

  float acc[8][16];
#pragma unroll
  for (int i = 0; i < 8; ++i)
#pragma unroll
    for (int u = 0; u < 16; ++u) acc[i][u] = 0.f;

  float s1r = 0.f, s2r = 0.f;

  const int at = tid >> 2, aq = tid & 3;
  const int bk = (tid >> 7) * 8;
  const int bj = (tid & 127) * 4;
  const float* tokp = tokens + (size_t)b * NT * DD + at * DD + aq * 4;
  const float* w1p = w1 + bk * HH + bj;

  float4 pA = *(const float4*)(tokp);
  float4 pB[8];
#pragma unroll
  for (int u = 0; u < 8; ++u) pB[u] = *(const float4*)(w1p + u * HH);

  for (int c = 0; c < NCHUNK; ++c) {
    const int k0 = c * KC;
    __syncthreads();
    Asm[aq * 4 + 0][at] = pA.x;
    Asm[aq * 4 + 1][at] = pA.y;
    Asm[aq * 4 + 2][at] = pA.z;
    Asm[aq * 4 + 3][at] = pA.w;
#pragma unroll
    for (int u = 0; u < 8; ++u) {
      float g = gam[k0 + bk + u];
      float4 v = pB[u];
      v.x *= g; v.y *= g; v.z *= g; v.w *= g;
      *(float4*)(&Bsm[bk + u][bj]) = v;
    }
    __syncthreads();
    if (c + 1 < NCHUNK) {
      tokp += KC;
      w1p += KC * HH;
      pA = *(const float4*)(tokp);
#pragma unroll
      for (int u = 0; u < 8; ++u) pB[u] = *(const float4*)(w1p + u * HH);
    }
    {
      const int t = tid & 63, kq = tid >> 6;
#pragma unroll
      for (int q = 0; q < 4; ++q) {
        float v = Asm[kq * 4 + q][t];
        s1r += v;
        s2r = fmaf(v, v, s2r);
      }
    }
    {
      const int kk = tid >> 4, tq = tid & 15;
      float v = 0.f;
#pragma unroll
      for (int q = 0; q < 4; ++q) v += Asm[kk][tq * 4 + q];
      v += __shfl_down(v, 8, 16);
      v += __shfl_down(v, 4, 16);
      v += __shfl_down(v, 2, 16);
      v += __shfl_down(v, 1, 16);
      if (tq == 0) colsum[k0 + kk] += v;
    }
#pragma unroll 4
    for (int k = 0; k < KC; ++k) {
      float4 A0 = *(const float4*)(&Asm[k][tg * 8]);
      float4 A1 = *(const float4*)(&Asm[k][tg * 8 + 4]);
      float4 B0 = *(const float4*)(&Bsm[k][hg * 4]);
      float4 B1 = *(const float4*)(&Bsm[k][128 + hg * 4]);
      float4 B2 = *(const float4*)(&Bsm[k][256 + hg * 4]);
      float4 B3 = *(const float4*)(&Bsm[k][384 + hg * 4]);
      const float av[8] = {A0.x, A0.y, A0.z, A0.w, A1.x, A1.y, A1.z, A1.w};
      const float bv[16] = {B0.x, B0.y, B0.z, B0.w, B1.x, B1.y, B1.z, B1.w,
                            B2.x, B2.y, B2.z, B2.w, B3.x, B3.y, B3.z, B3.w};
#pragma unroll
      for (int i = 0; i < 8; ++i)
#pragma unroll
        for (int u = 0; u < 16; ++u)
          acc[i][u] = fmaf(av[i], bv[u], acc[i][u]);
    }
  }

  {
    const int t = tid & 63, kq = tid >> 6;
    s1p[kq][t] = s1r;
    s2p[kq][t] = s2r;
  }
  __syncthreads();
  if (tid < NT) {
    float s1 = s1p[0][tid] + s1p[1][tid] + s1p[2][tid] + s1p[3][tid];
    float s2 = s2p[0][tid] + s2p[1][tid] + s2p[2][tid] + s2p[3][tid];
    float mu = s1 * (1.0f / DD);
    float var = s2 * (1.0f / DD) - mu * mu;
    float r = 1.0f / sqrtf(var + 1e-5f);
    r_s[tid] = r;
    rmu_s[tid] = r * mu;
  }
  __syncthreads();

  {
    float4 C1[4], C2[4], W2[4];
#pragma unroll
    for (int d = 0; d < 4; ++d) {
      C1[d] = sum4seg(c1p, d * 128 + hg * 4);
      C2[d] = sum4seg(c2p, d * 128 + hg * 4);
      W2[d] = *(const float4*)(w2 + d * 128 + hg * 4);
    }
    const float c1v[16] = {C1[0].x, C1[0].y, C1[0].z, C1[0].w,
                           C1[1].x, C1[1].y, C1[1].z, C1[1].w,
                           C1[2].x, C1[2].y, C1[2].z, C1[2].w,
                           C1[3].x, C1[3].y, C1[3].z, C1[3].w};
    const float c2v[16] = {C2[0].x, C2[0].y, C2[0].z, C2[0].w,
                           C2[1].x, C2[1].y, C2[1].z, C2[1].w,
                           C2[2].x, C2[2].y, C2[2].z, C2[2].w,
                           C2[3].x, C2[3].y, C2[3].z, C2[3].w};
    const float w2v[16] = {W2[0].x, W2[0].y, W2[0].z, W2[0].w,
                           W2[1].x, W2[1].y, W2[1].z, W2[1].w,
                           W2[2].x, W2[2].y, W2[2].z, W2[2].w,
                           W2[3].x, W2[3].y, W2[3].z, W2[3].w};
#pragma unroll
    for (int i = 0; i < 8; ++i) {
      int t = tg * 8 + i;
      float r = r_s[t], rm = rmu_s[t];
      float sp = 0.f;
#pragma unroll
      for (int u = 0; u < 16; ++u) {
        float h = fmaf(r, acc[i][u], fmaf(-rm, c1v[u], c2v[u]));
        h = fmaxf(h, 0.f);
        sp = fmaf(h, w2v[u], sp);
      }
      scp[hg][t] = sp;
    }
  }
  __syncthreads();

  if (tid < NT) {
    float s = 0.f;
#pragma unroll
    for (int h = 0; h < 32; ++h) s += scp[h][tid];
    int idx = tid;
    for (int it = 0; it < KTOP; ++it) {
      float bs = s;
      int bi = idx;
#pragma unroll
      for (int off = 32; off > 0; off >>= 1) {
        float os = __shfl_xor(bs, off);
        int oi = __shfl_xor(bi, off);
        if (os > bs || (os == bs && oi < bi)) { bs = os; bi = oi; }
      }
      if (tid == 0) topk_s[it] = bi;
      if (idx == bi) s = -INFINITY;
    }
  }
  __syncthreads();

  {
    const float* tb = tokens + (size_t)b * NT * DD;
    float* ob = out + (size_t)b * 16 * DD;
    float4 sel = {0.f, 0.f, 0.f, 0.f};
#pragma unroll
    for (int sI = 0; sI < KTOP; ++sI) {
      int t = topk_s[sI];
      float4 v = *(const float4*)(tb + t * DD + tid * 4);
      *(float4*)(ob + (1 + sI) * DD + tid * 4) = v;
      sel.x += v.x; sel.y += v.y; sel.z += v.z; sel.w += v.w;
    }
    float4 cs = *(const float4*)(&colsum[tid * 4]);
    const float inv = 1.0f / 49.0f;
    float4 bg;
    bg.x = (cs.x - sel.x) * inv;
    bg.y = (cs.y - sel.y) * inv;
    bg.z = (cs.z - sel.z) * inv;
    bg.w = (cs.w - sel.w) * inv;
    *(float4*)(ob + tid * 4) = bg;
  }
}

extern "C" void kernel_launch(void* const* d_in, const int* in_sizes, int n_in,
                              void* d_out, int out_size, void* d_ws, size_t ws_size,
                              hipStream_t stream) {
  const float* tokens = (const float*)d_in[0];
  const float* gamma  = (const float*)d_in[1];
  const float* beta   = (const float*)d_in[2];
  const float* w1     = (const float*)d_in[3];
  const float* b1     = (const float*)d_in[4];
  const float* w2     = (const float*)d_in[5];
  // d_in[6] = b2: constant shift, cannot change top-k selection/order -> unused.
  float* out = (float*)d_out;

  float* c1p = (float*)d_ws;                       // [4][512] f32 partials
  float* c2p = c1p + 4 * HH;                       // [4][512]
  int* flags = (int*)(c2p + 4 * HH);               // [2048]
  unsigned short* wth = (unsigned short*)((char*)d_ws + 24576);  // [512][1024] bf16
  unsigned short* wtl = wth + (size_t)HH * DD;
  const size_t need = 24576 + (size_t)HH * DD * 2 * 2;

  if (ws_size >= need) {
    prep_kernel<<<dim3(2, 4), 256, 0, stream>>>(w1, gamma, beta, b1, c1p, c2p, wth, wtl);
    fused_kernel<<<NB, 512, 0, stream>>>(tokens, c1p, c2p, w2, wth, wtl, flags, out);
    score_gather_kernel<<<NB, 256, 0, stream>>>(tokens, w1, w2, gamma, c1p, c2p, flags, out);
  } else {
    // workspace too small for the bf16 weight split: proven fp32 path only
    prep_kernel<<<dim3(2, 4), 256, 0, stream>>>(w1, gamma, beta, b1, c1p, c2p, nullptr, nullptr);
    score_gather_kernel<<<NB, 256, 0, stream>>>(tokens, w1, w2, gamma, c1p, c2p, nullptr, out);
  }
}